// Round 7
// baseline (151.299 us; speedup 1.0000x reference)
//
#include <hip/hip_runtime.h>
#include <math.h>

#define BB 64
#define II 1024
#define HH 1024

typedef float f4 __attribute__((ext_vector_type(4)));

// ws layout (floats)
#define WS_I     0
#define WS_F     64
#define WS_INVN  128
#define WS_DENOM 192
#define WS_O     256
#define WS_K     (256 + 65536)
#define WS_V     (256 + 2*65536)
#define WS_Q     (256 + 3*65536)
#define WS_XT    (256 + 4*65536)   // X transposed [k][b], 65536 floats

// ---------------- kernel 1: per-batch gates + input norm + X transpose ----------------
__global__ __launch_bounds__(64) void k_gates(const float* __restrict__ input,
                                              const float* __restrict__ if_w,
                                              const float* __restrict__ if_b,
                                              float* __restrict__ ws) {
    int b = blockIdx.x;
    int lane = threadIdx.x;
    const float4* x4 = (const float4*)(input + (size_t)b * II);
    const float4* w0 = (const float4*)(if_w);
    const float4* w1 = (const float4*)(if_w + II);
    float d0 = 0.f, d1 = 0.f, ss = 0.f;
#pragma unroll
    for (int j = 0; j < 4; ++j) {
        int idx = lane + j * 64;
        float4 xv = x4[idx];
        float4 a = w0[idx];
        float4 c = w1[idx];
        d0 += xv.x*a.x + xv.y*a.y + xv.z*a.z + xv.w*a.w;
        d1 += xv.x*c.x + xv.y*c.y + xv.z*c.z + xv.w*c.w;
        ss += xv.x*xv.x + xv.y*xv.y + xv.z*xv.z + xv.w*xv.w;
        // transpose X into ws (XT[k][b]) for coalesced consumption by k_mv
        int k = 4 * idx;
        ws[WS_XT + (size_t)(k+0) * 64 + b] = xv.x;
        ws[WS_XT + (size_t)(k+1) * 64 + b] = xv.y;
        ws[WS_XT + (size_t)(k+2) * 64 + b] = xv.z;
        ws[WS_XT + (size_t)(k+3) * 64 + b] = xv.w;
    }
#pragma unroll
    for (int off = 32; off > 0; off >>= 1) {
        d0 += __shfl_xor(d0, off);
        d1 += __shfl_xor(d1, off);
        ss += __shfl_xor(ss, off);
    }
    if (lane == 0) {
        ws[WS_I + b]    = expf(d0 + if_b[0]);
        ws[WS_F + b]    = expf(d1 + if_b[1]);
        ws[WS_INVN + b] = 1.0f / sqrtf(ss);
    }
}

// ---------------- kernel 2a: matvec partials, k-split for memory-level parallelism ----
// grid = 512 row-blocks x 8 k-blocks = 4096 blocks, 256 threads (4 waves).
// Wave w owns k-slice [kb*128 + w*32, +32); lane = batch; X from XT (coalesced,
// 32 scalar regs). 8 rows/block, weights read exactly once from HBM; unroll-2
// keeps ~16x16B in flight/wave; 8 blocks/CU x 4 waves -> ~8KB outstanding/CU.
// Partials -> pws[kb][b][gr] (in c_out region, overwritten later by k_cup).
__global__ __launch_bounds__(256) void k_mv(const float* __restrict__ ws,
                                            const float* __restrict__ o_w,
                                            const float* __restrict__ kvq_w,
                                            float* __restrict__ pws) {
    int t = threadIdx.x;
    int w = t >> 6, lane = t & 63;
    int kb = blockIdx.x >> 9;        // 0..7
    int rb = blockIdx.x & 511;       // 0..511
    int k0 = kb * 128 + w * 32;      // this wave's k-slice start

    // coalesced X-slice load: XT[k][b], lane = b
    const float* xt = ws + WS_XT + (size_t)k0 * 64;
    float xr[32];
#pragma unroll
    for (int j = 0; j < 32; ++j) xr[j] = xt[(size_t)j * 64 + lane];

    __shared__ float pl[8][4][64];

#pragma unroll 2
    for (int r = 0; r < 8; ++r) {
        int gr = rb * 8 + r;
        const float* wrow = (gr < HH) ? (o_w + (size_t)gr * II)
                                      : (kvq_w + (size_t)(gr - HH) * II);
        const f4* w4 = (const f4*)(wrow + k0);
        float a0 = 0.f, a1 = 0.f;
#pragma unroll
        for (int q = 0; q < 8; q += 2) {
            f4 u = w4[q], v = w4[q + 1];
            a0 += u.x*xr[4*q+0] + u.y*xr[4*q+1] + u.z*xr[4*q+2] + u.w*xr[4*q+3];
            a1 += v.x*xr[4*q+4] + v.y*xr[4*q+5] + v.z*xr[4*q+6] + v.w*xr[4*q+7];
        }
        pl[r][w][lane] = a0 + a1;
    }
    __syncthreads();

    if (t < 64) {                    // wave 0: reduce 4 wave-partials, write pws
        int b = t;
        float d[8];
#pragma unroll
        for (int r = 0; r < 8; ++r)
            d[r] = pl[r][0][b] + pl[r][1][b] + pl[r][2][b] + pl[r][3][b];
        f4 lo = {d[0], d[1], d[2], d[3]};
        f4 hi = {d[4], d[5], d[6], d[7]};
        f4* dst = (f4*)(pws + (((size_t)(kb * 64 + b)) << 12) + rb * 8);
        dst[0] = lo;
        dst[1] = hi;
    }
}

// ---------------- kernel 2b: reduce partials + epilogue + fused denom ----------------
// grid = 64 blocks (one per batch) x 256 threads; thread t handles h = 4t..4t+3
// for all four sections (o,k,v,q). All reads/writes coalesced per batch.
__global__ __launch_bounds__(256) void k_fin(const float* __restrict__ pws,
                                             const float* __restrict__ o_b,
                                             const float* __restrict__ kvq_b,
                                             const float* __restrict__ prev_n,
                                             float* __restrict__ ws,
                                             float* __restrict__ n_out) {
    int b = blockIdx.x;
    int t = threadIdx.x;
    int hh = 4 * t;
    float invn = ws[WS_INVN + b];
    float fb   = ws[WS_F + b];
    float ib   = ws[WS_I + b];
    const float* pb = pws + ((size_t)b << 12);

    f4 d[4];
#pragma unroll
    for (int p = 0; p < 4; ++p) {
        f4 s = {0.f, 0.f, 0.f, 0.f};
#pragma unroll
        for (int kb = 0; kb < 8; ++kb)
            s += *(const f4*)(pb + ((size_t)kb << 18) + p * 1024 + hh);
        d[p] = s;
    }

    // o = sigmoid(d0 + o_b)
    f4 ob = *(const f4*)(o_b + hh);
    f4 o;
    o.x = 1.f / (1.f + expf(-(d[0].x + ob.x)));
    o.y = 1.f / (1.f + expf(-(d[0].y + ob.y)));
    o.z = 1.f / (1.f + expf(-(d[0].z + ob.z)));
    o.w = 1.f / (1.f + expf(-(d[0].w + ob.w)));
    *(f4*)(ws + WS_O + (size_t)b * HH + hh) = o;

    // k = d1*invn/32 + kvq_b[0]; n = f*prev_n + i*k
    f4 kbias = *(const f4*)(kvq_b + hh);
    f4 kv = d[1] * (invn * 0.03125f) + kbias;
    *(f4*)(ws + WS_K + (size_t)b * HH + hh) = kv;
    f4 pn = *(const f4*)(prev_n + (size_t)b * HH + hh);
    f4 nn = pn * fb + kv * ib;
    *(f4*)(n_out + (size_t)b * HH + hh) = nn;

    // v = d2*invn + kvq_b[1]
    f4 vb = *(const f4*)(kvq_b + HH + hh);
    f4 vv = d[2] * invn + vb;
    *(f4*)(ws + WS_V + (size_t)b * HH + hh) = vv;

    // q = d3*invn + kvq_b[2]
    f4 qb = *(const f4*)(kvq_b + 2 * HH + hh);
    f4 qv = d[3] * invn + qb;
    *(f4*)(ws + WS_Q + (size_t)b * HH + hh) = qv;

    // fused denom: block-reduce sum(n*q)
    float s = nn.x*qv.x + nn.y*qv.y + nn.z*qv.z + nn.w*qv.w;
#pragma unroll
    for (int off = 32; off > 0; off >>= 1) s += __shfl_xor(s, off);
    __shared__ float red[4];
    if ((t & 63) == 0) red[t >> 6] = s;
    __syncthreads();
    if (t == 0)
        ws[WS_DENOM + b] = fmaxf(fabsf(red[0] + red[1] + red[2] + red[3]), 1.0f);
}

// ---------------- kernel 3: c update + fused readout h (R3 register version) ----------
__global__ __launch_bounds__(256) void k_cup(const float* __restrict__ prev_c,
                                             const float* __restrict__ ws,
                                             float* __restrict__ c_out,
                                             float* __restrict__ h_out) {
    int wave = threadIdx.x >> 6, lane = threadIdx.x & 63;
    int g0 = (blockIdx.x * 4 + wave) * 4;    // first of 4 rows, all same batch
    int b = g0 >> 10;
    float fb = ws[WS_F + b], ib = ws[WS_I + b];
    float iv0 = ib * ws[WS_V + g0];
    float iv1 = ib * ws[WS_V + g0 + 1];
    float iv2 = ib * ws[WS_V + g0 + 2];
    float iv3 = ib * ws[WS_V + g0 + 3];
    const f4* pc = (const f4*)(prev_c + ((size_t)g0 << 10));
    f4*       co = (f4*)(c_out + ((size_t)g0 << 10));
    const float4* k4 = (const float4*)(ws + WS_K + (size_t)b * HH);
    const float4* q4 = (const float4*)(ws + WS_Q + (size_t)b * HH);
    float s0 = 0.f, s1 = 0.f, s2 = 0.f, s3 = 0.f;
#pragma unroll
    for (int j = 0; j < 4; ++j) {
        int idx = lane + j * 64;
        float4 kv = k4[idx], qv = q4[idx];
        f4 p, c;
        p = __builtin_nontemporal_load(&pc[idx]);
        c.x = fb*p.x + iv0*kv.x; c.y = fb*p.y + iv0*kv.y;
        c.z = fb*p.z + iv0*kv.z; c.w = fb*p.w + iv0*kv.w;
        __builtin_nontemporal_store(c, &co[idx]);
        s0 += c.x*qv.x + c.y*qv.y + c.z*qv.z + c.w*qv.w;

        p = __builtin_nontemporal_load(&pc[idx + 256]);
        c.x = fb*p.x + iv1*kv.x; c.y = fb*p.y + iv1*kv.y;
        c.z = fb*p.z + iv1*kv.z; c.w = fb*p.w + iv1*kv.w;
        __builtin_nontemporal_store(c, &co[idx + 256]);
        s1 += c.x*qv.x + c.y*qv.y + c.z*qv.z + c.w*qv.w;

        p = __builtin_nontemporal_load(&pc[idx + 512]);
        c.x = fb*p.x + iv2*kv.x; c.y = fb*p.y + iv2*kv.y;
        c.z = fb*p.z + iv2*kv.z; c.w = fb*p.w + iv2*kv.w;
        __builtin_nontemporal_store(c, &co[idx + 512]);
        s2 += c.x*qv.x + c.y*qv.y + c.z*qv.z + c.w*qv.w;

        p = __builtin_nontemporal_load(&pc[idx + 768]);
        c.x = fb*p.x + iv3*kv.x; c.y = fb*p.y + iv3*kv.y;
        c.z = fb*p.z + iv3*kv.z; c.w = fb*p.w + iv3*kv.w;
        __builtin_nontemporal_store(c, &co[idx + 768]);
        s3 += c.x*qv.x + c.y*qv.y + c.z*qv.z + c.w*qv.w;
    }
#pragma unroll
    for (int off = 32; off > 0; off >>= 1) {
        s0 += __shfl_xor(s0, off);
        s1 += __shfl_xor(s1, off);
        s2 += __shfl_xor(s2, off);
        s3 += __shfl_xor(s3, off);
    }
    if (lane == 0) {
        float inv_d = 1.0f / ws[WS_DENOM + b];
        h_out[g0]     = ws[WS_O + g0]     * s0 * inv_d;
        h_out[g0 + 1] = ws[WS_O + g0 + 1] * s1 * inv_d;
        h_out[g0 + 2] = ws[WS_O + g0 + 2] * s2 * inv_d;
        h_out[g0 + 3] = ws[WS_O + g0 + 3] * s3 * inv_d;
    }
}

extern "C" void kernel_launch(void* const* d_in, const int* in_sizes, int n_in,
                              void* d_out, int out_size, void* d_ws, size_t ws_size,
                              hipStream_t stream) {
    const float* input  = (const float*)d_in[0];
    const float* prev_c = (const float*)d_in[2];
    const float* prev_n = (const float*)d_in[3];
    const float* if_w   = (const float*)d_in[4];
    const float* o_w    = (const float*)d_in[5];
    const float* kvq_w  = (const float*)d_in[6];
    const float* if_b   = (const float*)d_in[7];
    const float* o_b    = (const float*)d_in[8];
    const float* kvq_b  = (const float*)d_in[9];

    float* out   = (float*)d_out;
    float* h_out = out;                          // [B,H]
    float* c_out = out + 65536;                  // [B,H,H]
    float* n_out = out + 65536 + 67108864;       // [B,H]
    float* ws    = (float*)d_ws;
    float* pws   = c_out;                        // partials scratch inside c region
                                                 // (k_fin consumes before k_cup overwrites)

    k_gates<<<BB, 64, 0, stream>>>(input, if_w, if_b, ws);
    k_mv   <<<4096, 256, 0, stream>>>(ws, o_w, kvq_w, pws);
    k_fin  <<<BB, 256, 0, stream>>>(pws, o_b, kvq_b, prev_n, ws, n_out);
    k_cup  <<<4096, 256, 0, stream>>>(prev_c, ws, c_out, h_out);
}